// Round 5
// baseline (81.326 us; speedup 1.0000x reference)
//
#include <hip/hip_runtime.h>

// Multinomial via sum tree — SINGLE fused kernel, no grid barrier.
//
// R3 lesson: a full grid barrier (threadfence = per-wave L2 wb/inv across 8
// non-coherent XCDs) costs ~150 us. Here the ONLY cross-block traffic is 512
// chunk-sum floats via agent-scope atomics (LLC-coherent, no cache flush).
// Everything else is recomputed locally from READ-ONLY inputs:
//   phase A: block b sums leaves [4096b, 4096(b+1)) with the reference's
//            exact pairwise association; publishes chunk[b] (agent atomic).
//            Readiness test: ws poison 0xAA = -3.0e-13 < 0; sums ~2048 > 0.
//   phase B: spin-read all 512 chunk sums; rebuild tree levels 0..9 in LDS.
//   phase C: 2048 stratified samples/block, 8/thread: 9 steps in the top
//            tree -> level-9 chunk n + residual. Samples are monotone in s,
//            so each block touches a contiguous n-range (typically 2). For
//            each n: load its 4096 leaves from prio (read-only), rebuild the
//            12-level subtree in LDS, finish the last 12 steps from LDS.
// Deadlock-safety: publish happens BEFORE any spin; 512 blocks at 36 KB LDS
// and __launch_bounds__(256,4) -> >=4 blocks/CU -> capacity 1024 >= 512, so
// all blocks are co-resident (2x margin).
// All float sums use the reference association -> absmax 0.

#define NSAMP  (1 << 20)
#define NCHUNK 512
#define CHLEAF 4096

__global__ __launch_bounds__(256, 4) void fused(const float* __restrict__ prio,
                                                const float* __restrict__ uniform,
                                                float* chunkpub,
                                                int* __restrict__ out) {
    __shared__ float topT[1023];                 // levels 0..9 (512 chunk leaves)
    __shared__ __align__(16) float subT[8192];   // 1-indexed heap, leaves 4096..8191
    __shared__ int nrange[2];
    const int b = blockIdx.x, t = threadIdx.x;

    // ---- Phase A: exact chunk sum, publish ------------------------------
    {
        const float4* p4 = (const float4*)(prio + (size_t)b * CHLEAF);
        float4 a0 = p4[4*t], a1 = p4[4*t+1], a2 = p4[4*t+2], a3 = p4[4*t+3];
        float q0 = (a0.x + a0.y) + (a0.z + a0.w);
        float q1 = (a1.x + a1.y) + (a1.z + a1.w);
        float q2 = (a2.x + a2.y) + (a2.z + a2.w);
        float q3 = (a3.x + a3.y) + (a3.z + a3.w);
        subT[t] = (q0 + q1) + (q2 + q3);         // 16-leaf sum, ref association
        __syncthreads();
        float* src = subT;                       // ping-pong pairwise reduce
        float* dst = subT + 256;
        for (int cnt = 128; cnt >= 1; cnt >>= 1) {
            if (t < cnt) dst[t] = src[2*t] + src[2*t+1];
            __syncthreads();
            float* tmp = src; src = dst; dst = tmp;
        }
        if (t == 0)
            __hip_atomic_store(&chunkpub[b], src[0],
                               __ATOMIC_RELAXED, __HIP_MEMORY_SCOPE_AGENT);
    }

    // ---- Phase B: gather all chunk sums (spin), build top tree ----------
    for (int i = t; i < NCHUNK; i += 256) {
        float v = __hip_atomic_load(&chunkpub[i],
                                    __ATOMIC_RELAXED, __HIP_MEMORY_SCOPE_AGENT);
        while (!(v > 0.0f)) {                    // poison 0xAA.. is negative
            __builtin_amdgcn_s_sleep(2);
            v = __hip_atomic_load(&chunkpub[i],
                                  __ATOMIC_RELAXED, __HIP_MEMORY_SCOPE_AGENT);
        }
        topT[511 + i] = v;
    }
    __syncthreads();
    {
        int off = 255, cnt = 256;                // internal levels 8..0
        while (cnt >= 1) {
            for (int i = t; i < cnt; i += 256) {
                int m = off + i;
                topT[m] = topT[2*m+1] + topT[2*m+2];
            }
            __syncthreads();
            off = (off - 1) >> 1;
            cnt >>= 1;
        }
    }

    // ---- Phase C: 2048 samples/block, 8 chains/thread -------------------
    const float total = topT[0];
    const float scale = total / (float)NSAMP;    // exact pow-2 divide
    const int base = b * 2048 + t;

    float s[8]; int id[8];
    #pragma unroll
    for (int q = 0; q < 8; ++q) {
        int j = base + 256 * q;
        s[q]  = uniform[j] * total / (float)NSAMP + scale * (float)j;  // == ref
        id[q] = 0;
    }
    #pragma unroll
    for (int d = 0; d < 9; ++d) {                // levels 1..9 from LDS
        #pragma unroll
        for (int q = 0; q < 8; ++q) {
            int left = 2 * id[q] + 1;
            float lv = topT[left];
            bool r = s[q] > lv;                  // ref: go_left = s <= lv
            s[q]  = r ? s[q] - lv : s[q];
            id[q] = r ? left + 1 : left;
        }
    }
    // contiguous chunk range for this block (s monotone in sample index)
    if (t == 0)   nrange[0] = id[0] - 511;
    if (t == 255) nrange[1] = id[7] - 511;
    __syncthreads();
    const int nlo = nrange[0], nhi = nrange[1];

    for (int n = nlo; n <= nhi; ++n) {
        // stage chunk n's 4096 leaves (read-only input -> no coherence issue)
        {
            const float4* p4 = (const float4*)(prio + (size_t)n * CHLEAF);
            float4* l4 = (float4*)(subT + 4096);
            #pragma unroll
            for (int r = 0; r < 4; ++r) l4[t + 256*r] = p4[t + 256*r];  // coalesced
        }
        __syncthreads();
        for (int cnt = 2048; cnt >= 2; cnt >>= 1) {   // parents [cnt, 2cnt)
            for (int i = t; i < cnt; i += 256) {
                int k = cnt + i;
                subT[k] = subT[2*k] + subT[2*k+1];
            }
            __syncthreads();
        }
        #pragma unroll
        for (int q = 0; q < 8; ++q) {
            if (id[q] - 511 == n) {
                int k = 1;                        // 1-indexed: children 2k, 2k+1
                float ss = s[q];
                #pragma unroll
                for (int d = 0; d < 12; ++d) {
                    int left = 2 * k;
                    float lv = subT[left];
                    bool r = ss > lv;
                    ss = r ? ss - lv : ss;
                    k  = left + (r ? 1 : 0);
                }
                out[base + 256 * q] = n * CHLEAF + (k - 4096);
            }
        }
        __syncthreads();                          // subT reused next iteration
    }
}

extern "C" void kernel_launch(void* const* d_in, const int* in_sizes, int n_in,
                              void* d_out, int out_size, void* d_ws, size_t ws_size,
                              hipStream_t stream) {
    const float* prio    = (const float*)d_in[0];   // [2^21]
    const float* uniform = (const float*)d_in[1];   // [2^20]
    (void)in_sizes; (void)n_in; (void)out_size; (void)ws_size;

    float* chunkpub = (float*)d_ws;                 // 512 floats, poisoned 0xAA (<0)

    fused<<<NCHUNK, 256, 0, stream>>>(prio, uniform, chunkpub, (int*)d_out);
}

// Round 6
// 76.435 us; speedup vs baseline: 1.0640x; 1.0640x over previous
//
#include <hip/hip_runtime.h>

// Multinomial via sum tree — two kernels (best-measured structure, R2: 76.08us).
//
// Session findings baked in:
//  - dur_us = ~70us fixed harness floor (268MB ws re-poison fill @ ~80% HBM
//    peak + restores) + my kernel time (~6us). Only the latter is controllable.
//  - Grid barrier (R3): +150us — per-wave threadfence = L2 wb/inv across 8
//    non-coherent XCDs. Never again on this chip.
//  - Single-kernel fusion with agent-scope spin (R5): +5us vs two launches —
//    spin-gather + redundant per-block subtree rebuilds cost more than a launch.
//  - vEB blocked layout for levels 13-18 (R4): neutral (76.56 vs 76.08, noise) —
//    the 6 global hops are already L1/L2-resident via stratified locality.
//
// CAP=2^21 leaves, NSAMP=2^20 stratified samples, 21 traversal steps.
// ws tree holds internal levels 9..18 (slots 511..524286, root-first layout,
// 2MB). Levels 19,20 + leaf compare: in-register from one 32B prio load.
// Levels 0..12: staged/rebuilt per-block in LDS (exact pairwise sums ->
// bit-identical to reference tree; absmax 0.0 verified every round).

#define CAP    (1 << 21)
#define NSAMP  (1 << 20)
#define L18OFF ((1 << 18) - 1)   // 262143

// ---- Build internal levels 18..9: 512 blocks x 256 thr, 4096 leaves/block
__global__ __launch_bounds__(256) void build_tree(const float* __restrict__ prio,
                                                  float* __restrict__ tree) {
    __shared__ __align__(16) float A[512];
    __shared__ __align__(16) float B[256];
    const int b = blockIdx.x, t = threadIdx.x;
    const float4* p4 = (const float4*)(prio + (size_t)b * 4096);

    // level 18: each node = 8-leaf sum, reference association.
    #pragma unroll
    for (int i = t; i < 512; i += 256) {
        float4 x = p4[2 * i], y = p4[2 * i + 1];
        A[i] = ((x.x + x.y) + (x.z + x.w)) + ((y.x + y.y) + (y.z + y.w));
    }
    __syncthreads();
    {
        float* g = tree + L18OFF + b * 512;
        #pragma unroll
        for (int i = t; i < 512; i += 256) g[i] = A[i];   // coalesced
    }
    // levels 17..9 via LDS ping-pong (exact pairwise sums).
    float* src = A;
    float* dst = B;
    int cnt = 256;
    int off = (1 << 17) - 1;
    for (int lvl = 17; lvl >= 9; --lvl) {
        for (int i = t; i < cnt; i += 256) {
            float2 v = ((const float2*)src)[i];
            float r = v.x + v.y;
            dst[i] = r;
            tree[off + b * cnt + i] = r;
        }
        __syncthreads();
        float* tmp = src; src = dst; dst = tmp;
        off = (off - 1) >> 1;
        cnt >>= 1;
    }
}

// ---- Sample: 1024 blocks x 256 threads x 4 chains/thread (ILP) ----------
__global__ __launch_bounds__(256) void sample_kernel(const float* __restrict__ tree,
                                                     const float* __restrict__ prio,
                                                     const float* __restrict__ uniform,
                                                     int* __restrict__ out) {
    __shared__ float nds[8191];          // nodes 0..8190 = levels 0..12 (32 KB)
    const int t = threadIdx.x;

    for (int i = 511 + t; i < 8191; i += 256) nds[i] = tree[i];  // levels 9..12
    __syncthreads();
    {
        int cnt = 256, off = 255;        // rebuild levels 8..0 (exact sums)
        for (int lvl = 8; lvl >= 0; --lvl) {
            for (int i = t; i < cnt; i += 256) {
                int n = off + i;
                nds[n] = nds[2 * n + 1] + nds[2 * n + 2];
            }
            __syncthreads();
            off = (off - 1) >> 1;
            cnt >>= 1;
        }
    }

    const float total = nds[0];
    const float scale = total / (float)NSAMP;     // exact pow-2 divide
    const int base = blockIdx.x * 1024 + t;

    float s[4];
    int   id[4];
    #pragma unroll
    for (int q = 0; q < 4; ++q) {
        int j = base + 256 * q;
        s[q]  = uniform[j] * total / (float)NSAMP + scale * (float)j;  // == ref
        id[q] = 0;
    }

    #pragma unroll
    for (int d = 0; d < 12; ++d) {       // levels 1..12 from LDS
        #pragma unroll
        for (int q = 0; q < 4; ++q) {
            int left = 2 * id[q] + 1;
            float lv = nds[left];
            bool r = s[q] > lv;          // ref: go_left = s <= lv
            s[q]  = r ? s[q] - lv : s[q];
            id[q] = r ? left + 1 : left;
        }
    }
    #pragma unroll
    for (int d = 0; d < 6; ++d) {        // levels 13..18 from global (L1/L2-hot)
        #pragma unroll
        for (int q = 0; q < 4; ++q) {
            int left = 2 * id[q] + 1;
            float lv = tree[left];
            bool r = s[q] > lv;
            s[q]  = r ? s[q] - lv : s[q];
            id[q] = r ? left + 1 : left;
        }
    }
    #pragma unroll
    for (int q = 0; q < 4; ++q) {        // levels 19,20 + leaf in-register
        int p = id[q] - L18OFF;
        const float4* pp = (const float4*)prio + 2 * (size_t)p;
        float4 x = pp[0], y = pp[1];     // leaves 8p..8p+7
        float l19 = (x.x + x.y) + (x.z + x.w);
        bool r1 = s[q] > l19;
        float ss = r1 ? s[q] - l19 : s[q];
        float l20 = r1 ? (y.x + y.y) : (x.x + x.y);
        bool r2 = ss > l20;
        ss = r2 ? ss - l20 : ss;
        float leaf = r1 ? (r2 ? y.z : y.x) : (r2 ? x.z : x.x);
        bool r3 = ss > leaf;
        out[base + 256 * q] = 8 * p + (r1 ? 4 : 0) + (r2 ? 2 : 0) + (r3 ? 1 : 0);
    }
}

extern "C" void kernel_launch(void* const* d_in, const int* in_sizes, int n_in,
                              void* d_out, int out_size, void* d_ws, size_t ws_size,
                              hipStream_t stream) {
    const float* prio    = (const float*)d_in[0];   // [CAP]
    const float* uniform = (const float*)d_in[1];   // [NSAMP]
    (void)in_sizes; (void)n_in; (void)out_size; (void)ws_size;

    float* tree = (float*)d_ws;    // 2^19-1 floats; slots 511..524286 used

    build_tree<<<512, 256, 0, stream>>>(prio, tree);
    sample_kernel<<<NSAMP / 1024, 256, 0, stream>>>(tree, prio, uniform, (int*)d_out);
}